// Round 12
// baseline (206.951 us; speedup 1.0000x reference)
//
#include <hip/hip_runtime.h>
#include <hip/hip_bf16.h>
#include <type_traits>

#define DEV __device__ __forceinline__

typedef __attribute__((ext_vector_type(4))) float f32x4;
typedef __attribute__((ext_vector_type(16))) float f32x16;
typedef __attribute__((ext_vector_type(8))) short short8;

static constexpr int Bc = 2, Sc = 2048, HQc = 32, HKVc = 8;

DEV unsigned short f2bf(float f) {
  union { float f; unsigned u; } v; v.f = f;
  unsigned r = v.u + 0x7fffu + ((v.u >> 16) & 1u);
  return (unsigned short)(r >> 16);
}
DEV float bf2f(unsigned short u) {
  union { unsigned u; float f; } v; v.u = ((unsigned)u) << 16;
  return v.f;
}

typedef const unsigned __attribute__((address_space(1)))* gp1;
typedef unsigned __attribute__((address_space(3)))* lp3;
DEV void gload16(const void* g, void* l) {
  __builtin_amdgcn_global_load_lds((gp1)g, (lp3)l, 16, 0, 0);
}

DEV unsigned cvt_pk_bf16(float lo, float hi) {
  unsigned r;
  asm("v_cvt_pk_bf16_f32 %0, %1, %2" : "=v"(r) : "v"(lo), "v"(hi));
  return r;
}
DEV void pl32swap(unsigned& a, unsigned& b) {
  asm("v_permlane32_swap_b32 %0, %1" : "+v"(a), "+v"(b));
}

// ---------------- cast x (f32 -> bf16, same layout) ----------------
__global__ __launch_bounds__(256) void cast_x(const float* __restrict__ in,
                                              unsigned short* __restrict__ out) {
  const size_t i = (size_t)blockIdx.x * 256 + threadIdx.x;
  const float4 v = reinterpret_cast<const float4*>(in)[i];
  ushort4 o;
  o.x = f2bf(v.x); o.y = f2bf(v.y); o.z = f2bf(v.z); o.w = f2bf(v.w);
  reinterpret_cast<ushort4*>(out)[i] = o;
}

// ---------------- transpose-cast weight: f32 [K][N] -> bf16 [N][K] ----------------
__global__ __launch_bounds__(256) void wtrans(const float* __restrict__ in,
                                              unsigned short* __restrict__ out,
                                              int K, int N) {
  __shared__ float t[64][65];
  const int tid = threadIdx.x;
  const int n0 = blockIdx.x * 64, k0 = blockIdx.y * 64;
#pragma unroll
  for (int p = 0; p < 4; ++p) {
    const int kr = p * 16 + (tid >> 4);
    const int c = (tid & 15) * 4;
    const float4 v = *reinterpret_cast<const float4*>(&in[(size_t)(k0 + kr) * N + n0 + c]);
    t[c + 0][kr] = v.x; t[c + 1][kr] = v.y; t[c + 2][kr] = v.z; t[c + 3][kr] = v.w;
  }
  __syncthreads();
  const int n = tid >> 2, kc = (tid & 3) * 16;
  union { unsigned short u[16]; uint4 q[2]; } o;
#pragma unroll
  for (int e = 0; e < 16; ++e) o.u[e] = f2bf(t[n][kc + e]);
  uint4* dst = reinterpret_cast<uint4*>(&out[(size_t)(n0 + n) * K + k0 + kc]);
  dst[0] = o.q[0]; dst[1] = o.q[1];
}

// ---------------- GEMM: C(MxN) = A(MxK,bf16) * Bt(NxK,bf16)^T, m97 structure ----------------
// flat 1D grid with bijective XCD swizzle (m204)
template <typename CT>
__global__ __launch_bounds__(256) void gemm_bt(const unsigned short* __restrict__ A,
                                               const unsigned short* __restrict__ Bt,
                                               CT* __restrict__ C, int M, int N, int K,
                                               int gx) {
  const int nwg = gridDim.x;
  int bid = blockIdx.x;
  {
    const int qq = nwg >> 3, rr = nwg & 7;
    const int xcd = bid & 7, lid = bid >> 3;
    bid = (xcd < rr ? xcd * (qq + 1) : rr * (qq + 1) + (xcd - rr) * qq) + lid;
  }
  const int m0 = (bid / gx) * 128, n0 = (bid % gx) * 128;
  __shared__ __align__(16) unsigned short As[128 * 64];
  __shared__ __align__(16) unsigned short Bs[128 * 64];
  const int tid = threadIdx.x;
  const int w = tid >> 6, lane = tid & 63;
  const int g = lane >> 4, lm = lane & 15;
  const int wr = w >> 1, wc = w & 1;
  f32x4 acc[4][4] = {};
  const int nk = K >> 6;
  const char* Abase = (const char*)(A + (size_t)m0 * K);
  const char* Bbase = (const char*)(Bt + (size_t)n0 * K);
  const int off = w * 4096 + 16 * lane;
  for (int kt = 0; kt < nk; ++kt) {
    __syncthreads();
#pragma unroll
    for (int i = 0; i < 4; ++i) {
      const int o = off + i * 1024;
      const int row = o >> 7;
      const int kbs = (o & 127) ^ ((row & 7) << 4);
      const size_t gof = (size_t)row * (2 * K) + (size_t)kt * 128 + kbs;
      gload16(Abase + gof, (char*)As + (w * 4096 + i * 1024));
      gload16(Bbase + gof, (char*)Bs + (w * 4096 + i * 1024));
    }
    __syncthreads();
#pragma unroll
    for (int ks = 0; ks < 2; ++ks) {
      short8 af[4], bfr[4];
#pragma unroll
      for (int i = 0; i < 4; ++i) {
        const int ar = wr * 64 + i * 16 + lm;
        af[i] = *reinterpret_cast<const short8*>((const char*)As + ar * 128 + (((ks * 4 + g) ^ (ar & 7)) << 4));
        const int br = wc * 64 + i * 16 + lm;
        bfr[i] = *reinterpret_cast<const short8*>((const char*)Bs + br * 128 + (((ks * 4 + g) ^ (br & 7)) << 4));
      }
#pragma unroll
      for (int i = 0; i < 4; ++i)
#pragma unroll
        for (int j = 0; j < 4; ++j)
          acc[i][j] = __builtin_amdgcn_mfma_f32_16x16x32_bf16(af[i], bfr[j], acc[i][j], 0, 0, 0);
    }
  }
#pragma unroll
  for (int i = 0; i < 4; ++i)
#pragma unroll
    for (int j = 0; j < 4; ++j)
#pragma unroll
      for (int r = 0; r < 4; ++r) {
        const size_t idx = (size_t)(m0 + wr * 64 + i * 16 + g * 4 + r) * N + (n0 + wc * 64 + j * 16 + lm);
        if constexpr (std::is_same<CT, float>::value) C[idx] = acc[i][j][r];
        else C[idx] = (CT)f2bf(acc[i][j][r]);
      }
}

// ---------------- fused QKV GEMM: x[4096x2048] x Wqkv[3072x2048]^T ----------------
// Epilogue (all paths LDS-bounce -> coalesced stores):
//  n-tiles 0..15 -> Q (RoPE on bf16, *0.125*log2e -> Qbf[B][32][S][64])
//  n-tiles 16..19 -> K (RoPE -> Kbf[B][8][S][64])
//  n-tiles 20..23 -> V (transpose -> Vtb[B][8][64][S])
__global__ __launch_bounds__(256) void gemm_qkv(const unsigned short* __restrict__ A,
                                                const unsigned short* __restrict__ Bt,
                                                const float* __restrict__ cosT,
                                                const float* __restrict__ sinT,
                                                unsigned short* __restrict__ Qbf,
                                                unsigned short* __restrict__ Kbf,
                                                unsigned short* __restrict__ Vtb) {
  constexpr int K = 2048, gx = 24;
  int bid = blockIdx.x;
  { const int xcd = bid & 7, lid = bid >> 3; bid = xcd * 96 + lid; }  // 768 % 8 == 0
  const int m0 = (bid / gx) * 128, n0 = (bid % gx) * 128;
  __shared__ __align__(16) char sm[32768];
  unsigned short* As = (unsigned short*)sm;
  unsigned short* Bs = (unsigned short*)(sm + 16384);
  const int tid = threadIdx.x;
  const int w = tid >> 6, lane = tid & 63;
  const int g = lane >> 4, lm = lane & 15;
  const int wr = w >> 1, wc = w & 1;
  f32x4 acc[4][4] = {};
  const char* Abase = (const char*)(A + (size_t)m0 * K);
  const char* Bbase = (const char*)(Bt + (size_t)n0 * K);
  const int off = w * 4096 + 16 * lane;
  for (int kt = 0; kt < 32; ++kt) {
    __syncthreads();
#pragma unroll
    for (int i = 0; i < 4; ++i) {
      const int o = off + i * 1024;
      const int row = o >> 7;
      const int kbs = (o & 127) ^ ((row & 7) << 4);
      const size_t gof = (size_t)row * (2 * K) + (size_t)kt * 128 + kbs;
      gload16(Abase + gof, (char*)As + (w * 4096 + i * 1024));
      gload16(Bbase + gof, (char*)Bs + (w * 4096 + i * 1024));
    }
    __syncthreads();
#pragma unroll
    for (int ks = 0; ks < 2; ++ks) {
      short8 af[4], bfr[4];
#pragma unroll
      for (int i = 0; i < 4; ++i) {
        const int ar = wr * 64 + i * 16 + lm;
        af[i] = *reinterpret_cast<const short8*>((const char*)As + ar * 128 + (((ks * 4 + g) ^ (ar & 7)) << 4));
        const int br = wc * 64 + i * 16 + lm;
        bfr[i] = *reinterpret_cast<const short8*>((const char*)Bs + br * 128 + (((ks * 4 + g) ^ (br & 7)) << 4));
      }
#pragma unroll
      for (int i = 0; i < 4; ++i)
#pragma unroll
        for (int j = 0; j < 4; ++j)
          acc[i][j] = __builtin_amdgcn_mfma_f32_16x16x32_bf16(af[i], bfr[j], acc[i][j], 0, 0, 0);
    }
  }
  // ---------------- fused epilogue (LDS bounce; As/Bs dead) ----------------
  __syncthreads();
  unsigned short* Os = (unsigned short*)sm;
  if (n0 < 2560) {
    // stage acc as bf16: Os[row][col], col = wc*64 + j*16 + lm (= 2 heads x 64 d)
#pragma unroll
    for (int i = 0; i < 4; ++i)
#pragma unroll
      for (int j = 0; j < 4; ++j) {
        const int col = wc * 64 + j * 16 + lm;
#pragma unroll
        for (int r = 0; r < 4; ++r) {
          const int row = wr * 64 + i * 16 + g * 4 + r;
          Os[row * 128 + col] = f2bf(acc[i][j][r]);
        }
      }
    __syncthreads();
    const bool isQ = (n0 < 2048);
    const float qs = isQ ? 0.125f * 1.44269504089f : 1.0f;
    unsigned short* Base = isQ ? Qbf : Kbf;
    const int h0 = isQ ? (n0 >> 6) : ((n0 - 2048) >> 6);
    const int NH = isQ ? HQc : HKVc;
    // coalesced RoPE + store: cid covers 128 rows x 16 chunks of 16B
#pragma unroll
    for (int it = 0; it < 8; ++it) {
      const int cid = it * 256 + tid;
      const int row = cid >> 4, chunk = cid & 15;
      const int head = chunk >> 3, d0 = (chunk & 7) * 8;
      const int gm = m0 + row;
      const int b = gm >> 11, s = gm & (Sc - 1);
      union { unsigned short u[8]; uint4 q; } xs, xp;
      xs.q = *reinterpret_cast<const uint4*>(&Os[row * 128 + head * 64 + d0]);
      xp.q = *reinterpret_cast<const uint4*>(&Os[row * 128 + head * 64 + (d0 ^ 32)]);
      const float4 c0 = *reinterpret_cast<const float4*>(&cosT[s * 64 + d0]);
      const float4 c1 = *reinterpret_cast<const float4*>(&cosT[s * 64 + d0 + 4]);
      const float4 sn0 = *reinterpret_cast<const float4*>(&sinT[s * 64 + d0]);
      const float4 sn1 = *reinterpret_cast<const float4*>(&sinT[s * 64 + d0 + 4]);
      const float sgn = (d0 < 32) ? -1.f : 1.f;
      const float cc[8] = {c0.x, c0.y, c0.z, c0.w, c1.x, c1.y, c1.z, c1.w};
      const float ss[8] = {sn0.x, sn0.y, sn0.z, sn0.w, sn1.x, sn1.y, sn1.z, sn1.w};
      union { unsigned short u[8]; uint4 q; } o;
#pragma unroll
      for (int e = 0; e < 8; ++e)
        o.u[e] = f2bf((bf2f(xs.u[e]) * cc[e] + sgn * bf2f(xp.u[e]) * ss[e]) * qs);
      *reinterpret_cast<uint4*>(&Base[((size_t)(b * NH + h0 + head) * Sc + s) * 64 + d0]) = o.q;
    }
  } else {
    // V: transpose -> Vtb[B][HKV][64][S]; Os [2 wc][64 d][128 s], XOR-swizzled s
#pragma unroll
    for (int i = 0; i < 4; ++i)
#pragma unroll
      for (int j = 0; j < 4; ++j) {
        const int d = j * 16 + lm;
        const int xo = (d & 7) << 3;
#pragma unroll
        for (int r = 0; r < 4; ++r) {
          const int sl = wr * 64 + i * 16 + g * 4 + r;
          Os[(wc * 64 + d) * 128 + (sl ^ xo)] = f2bf(acc[i][j][r]);
        }
      }
    __syncthreads();
    const int rowid = tid >> 1, half = tid & 1;      // rowid: 0..127 = wc*64+d
    const int wcr = rowid >> 6, dd = rowid & 63;
    const int hk = ((n0 - 2560) >> 6) + wcr;
    const int b = m0 >> 11, sbase = (m0 & (Sc - 1)) + half * 64;
    unsigned short* dst = Vtb + ((size_t)(b * HKVc + hk) * 64 + dd) * Sc + sbase;
    const unsigned short* srcp = Os + (size_t)rowid * 128 + half * 64;
    const int xq = dd & 7;
#pragma unroll
    for (int q = 0; q < 8; ++q)
      reinterpret_cast<uint4*>(dst)[q] = *reinterpret_cast<const uint4*>(srcp + ((q ^ xq) * 8));
  }
}

// ---------------- causal GQA flash attention, 64-row q-tile + ones-MFMA l + setprio ----------------
__global__ __launch_bounds__(256, 4) void attn_fwd(const unsigned short* __restrict__ Qb,
                                                   const unsigned short* __restrict__ Kb,
                                                   const unsigned short* __restrict__ Vt,
                                                   unsigned short* __restrict__ Ob) {
  __shared__ __align__(16) char sm[32768];
  const int tid = threadIdx.x;
  const int w = tid >> 6, lane = tid & 63;
  const int lane31 = lane & 31, hi = lane >> 5;
  const int hi16 = hi * 16;
  const int hl = w >> 1, wh = w & 1;
  const int bid = blockIdx.x;
  const int hk = bid & 7;
  const int sub = (bid >> 3) & 3;
  const int tq = (bid >> 5) & 7;
  const int quarter = bid >> 8;
  int qt;
  if (quarter == 0) qt = 31 - tq;
  else if (quarter == 1) qt = 16 + tq;
  else if (quarter == 2) qt = 15 - tq;
  else qt = tq;
  const int b = sub >> 1, hp = sub & 1;
  const int h = hk * 4 + hp * 2 + hl;
  const int q0 = qt * 64;
  const char* Kbase = (const char*)(Kb + (size_t)(b * HKVc + hk) * Sc * 64);
  const char* Vbase = (const char*)(Vt + (size_t)(b * HKVc + hk) * 64 * Sc);
  const unsigned short* Qp = Qb + (((size_t)(b * HQc + h) * Sc) + q0 + wh * 32 + lane31) * 64;
  short8 qf[4];
#pragma unroll
  for (int c = 0; c < 4; ++c)
    qf[c] = *reinterpret_cast<const short8*>(Qp + c * 16 + hi * 8);

  f32x16 acc[2] = {};
  f32x16 accl = {};
  const int qlocal = wh * 32 + lane31 - 4 * hi;
  union { unsigned u[4]; short8 s; } onesu;
  onesu.u[0] = onesu.u[1] = onesu.u[2] = onesu.u[3] = 0x3f803f80u;
  const short8 ones8 = onesu.s;

  const int so0 = tid * 16;
  auto stage = [&](int kt, int buf) {
    char* Kd = sm + buf * 16384;
    char* Vd = sm + buf * 16384 + 8192;
#pragma unroll
    for (int q = 0; q < 2; ++q) {
      const int o = q * 4096 + so0;
      const int srow = o >> 7;
      const int kbs = (o & 127) ^ ((srow & 7) << 4);
      const int ld = q * 4096 + w * 1024;
      gload16(Kbase + (size_t)(kt * 64 + srow) * 128 + kbs, Kd + ld);
      gload16(Vbase + (size_t)srow * (Sc * 2) + (size_t)kt * 128 + kbs, Vd + ld);
    }
  };

  stage(0, 0);
  __syncthreads();
  for (int kt = 0; kt <= qt; ++kt) {
    const int cur = kt & 1;
    if (kt < qt) stage(kt + 1, cur ^ 1);
    const char* Kbuf = sm + cur * 16384;
    const char* Vbuf = sm + cur * 16384 + 8192;
    const bool dg = (kt == qt);
    const bool do_hi = !dg || (wh == 1);
    short8 pf[4];
    {
      f32x16 st = {};
      __builtin_amdgcn_s_setprio(1);
#pragma unroll
      for (int c = 0; c < 4; ++c) {
        const int row = lane31;
        const short8 kf = *reinterpret_cast<const short8*>(Kbuf + row * 128 + ((c * 32 + hi16) ^ ((row & 7) << 4)));
        st = __builtin_amdgcn_mfma_f32_32x32x16_bf16(kf, qf[c], st, 0, 0, 0);
      }
      __builtin_amdgcn_s_setprio(0);
      if (dg && wh == 0) {
#pragma unroll
        for (int r = 0; r < 16; ++r) {
          const int kl = (r & 3) + 8 * (r >> 2);
          st[r] = exp2f(kl > qlocal ? -1e30f : st[r]);
        }
      } else {
#pragma unroll
        for (int r = 0; r < 16; ++r) st[r] = exp2f(st[r]);
      }
      union { unsigned u[4]; short8 s; } x, y;
      unsigned a0 = cvt_pk_bf16(st[0], st[1]), b0 = cvt_pk_bf16(st[4], st[5]);
      pl32swap(a0, b0);
      unsigned a1 = cvt_pk_bf16(st[2], st[3]), b1 = cvt_pk_bf16(st[6], st[7]);
      pl32swap(a1, b1);
      x.u[0] = a0; x.u[1] = a1; x.u[2] = b0; x.u[3] = b1; pf[0] = x.s;
      unsigned a2 = cvt_pk_bf16(st[8], st[9]), b2 = cvt_pk_bf16(st[12], st[13]);
      pl32swap(a2, b2);
      unsigned a3 = cvt_pk_bf16(st[10], st[11]), b3 = cvt_pk_bf16(st[14], st[15]);
      pl32swap(a3, b3);
      y.u[0] = a2; y.u[1] = a3; y.u[2] = b2; y.u[3] = b3; pf[1] = y.s;
    }
    if (do_hi) {
      f32x16 st = {};
      __builtin_amdgcn_s_setprio(1);
#pragma unroll
      for (int c = 0; c < 4; ++c) {
        const int row = 32 + lane31;
        const short8 kf = *reinterpret_cast<const short8*>(Kbuf + row * 128 + ((c * 32 + hi16) ^ ((row & 7) << 4)));
        st = __builtin_amdgcn_mfma_f32_32x32x16_bf16(kf, qf[c], st, 0, 0, 0);
      }
      __builtin_amdgcn_s_setprio(0);
      if (dg) {
        const int rhs = qlocal - 32;
#pragma unroll
        for (int r = 0; r < 16; ++r) {
          const int kl = (r & 3) + 8 * (r >> 2);
          st[r] = exp2f(kl > rhs ? -1e30f : st[r]);
        }
      } else {
#pragma unroll
        for (int r = 0; r < 16; ++r) st[r] = exp2f(st[r]);
      }
      union { unsigned u[4]; short8 s; } x, y;
      unsigned a0 = cvt_pk_bf16(st[0], st[1]), b0 = cvt_pk_bf16(st[4], st[5]);
      pl32swap(a0, b0);
      unsigned a1 = cvt_pk_bf16(st[2], st[3]), b1 = cvt_pk_bf16(st[6], st[7]);
      pl32swap(a1, b1);
      x.u[0] = a0; x.u[1] = a1; x.u[2] = b0; x.u[3] = b1; pf[2] = x.s;
      unsigned a2 = cvt_pk_bf16(st[8], st[9]), b2 = cvt_pk_bf16(st[12], st[13]);
      pl32swap(a2, b2);
      unsigned a3 = cvt_pk_bf16(st[10], st[11]), b3 = cvt_pk_bf16(st[14], st[15]);
      pl32swap(a3, b3);
      y.u[0] = a2; y.u[1] = a3; y.u[2] = b2; y.u[3] = b3; pf[3] = y.s;
    }
    __builtin_amdgcn_s_setprio(1);
#pragma unroll
    for (int dt = 0; dt < 2; ++dt) {
      const int row = dt * 32 + lane31;
      const int rx = (row & 7) << 4;
#pragma unroll
      for (int c = 0; c < 2; ++c) {
        const short8 vf = *reinterpret_cast<const short8*>(Vbuf + row * 128 + ((c * 32 + hi16) ^ rx));
        acc[dt] = __builtin_amdgcn_mfma_f32_32x32x16_bf16(pf[c], vf, acc[dt], 0, 0, 0);
      }
      if (do_hi) {
#pragma unroll
        for (int c = 2; c < 4; ++c) {
          const short8 vf = *reinterpret_cast<const short8*>(Vbuf + row * 128 + ((c * 32 + hi16) ^ rx));
          acc[dt] = __builtin_amdgcn_mfma_f32_32x32x16_bf16(pf[c], vf, acc[dt], 0, 0, 0);
        }
      }
    }
    accl = __builtin_amdgcn_mfma_f32_32x32x16_bf16(pf[0], ones8, accl, 0, 0, 0);
    accl = __builtin_amdgcn_mfma_f32_32x32x16_bf16(pf[1], ones8, accl, 0, 0, 0);
    if (do_hi) {
      accl = __builtin_amdgcn_mfma_f32_32x32x16_bf16(pf[2], ones8, accl, 0, 0, 0);
      accl = __builtin_amdgcn_mfma_f32_32x32x16_bf16(pf[3], ones8, accl, 0, 0, 0);
    }
    __builtin_amdgcn_s_setprio(0);
    __syncthreads();
  }
  unsigned short* Os = (unsigned short*)sm;
#pragma unroll
  for (int r = 0; r < 16; ++r) {
    const int cr = (r & 3) + 8 * (r >> 2) + 4 * hi;
    const float inv = 1.f / accl[r];
    const int row = wh * 32 + cr;
#pragma unroll
    for (int dt = 0; dt < 2; ++dt)
      Os[row * 128 + hl * 64 + dt * 32 + lane31] = f2bf(acc[dt][r] * inv);
  }
  __syncthreads();
  unsigned short* Op = Ob + (size_t)(b * Sc + q0) * (HQc * 64) + (hk * 4 + hp * 2) * 64;
#pragma unroll
  for (int i = 0; i < 4; ++i) {
    const int cid = i * 256 + tid;
    const int row = cid >> 4;
    const int cb = (cid & 15) * 16;
    const uint4 v = *reinterpret_cast<const uint4*>(sm + row * 256 + cb);
    *reinterpret_cast<uint4*>((char*)(Op + (size_t)row * (HQc * 64)) + cb) = v;
  }
}

extern "C" void kernel_launch(void* const* d_in, const int* in_sizes, int n_in,
                              void* d_out, int out_size, void* d_ws, size_t ws_size,
                              hipStream_t stream) {
  (void)in_sizes; (void)n_in; (void)out_size; (void)ws_size;
  const float* x    = (const float*)d_in[0];
  const float* cosT = (const float*)d_in[1];
  const float* sinT = (const float*)d_in[2];
  // d_in[3] = mask: deterministic causal, not read
  const float* Wq = (const float*)d_in[4];
  const float* Wk = (const float*)d_in[5];
  const float* Wv = (const float*)d_in[6];
  const float* Wo = (const float*)d_in[7];
  float* out = (float*)d_out;
  char* ws = (char*)d_ws;
  const size_t MB = (size_t)1 << 20;
  // Workspace (60MB):
  unsigned short* xb   = (unsigned short*)(ws + 0 * MB);   // 16MB (x bf16; reused as Att)
  unsigned short* Wqkv = (unsigned short*)(ws + 16 * MB);  // 12MB packed [3072][2048] bf16
  unsigned short* Wot  = (unsigned short*)(ws + 28 * MB);  // 8MB
  unsigned short* Qbf  = (unsigned short*)(ws + 36 * MB);  // 16MB ([B][HQ][S][64])
  unsigned short* Kbf  = (unsigned short*)(ws + 52 * MB);  // 4MB
  unsigned short* Vtb  = (unsigned short*)(ws + 56 * MB);  // 4MB  -> 60MB total
  unsigned short* Att  = (unsigned short*)(ws + 0 * MB);   // reuse xb (dead after QKV GEMM)

  cast_x<<<2097152 / 256, 256, 0, stream>>>(x, xb);
  wtrans<<<dim3(32, 32), 256, 0, stream>>>(Wq, Wqkv, 2048, 2048);                     // rows 0..2047
  wtrans<<<dim3(8, 32), 256, 0, stream>>>(Wk, Wqkv + (size_t)2048 * 2048, 2048, 512); // rows 2048..2559
  wtrans<<<dim3(8, 32), 256, 0, stream>>>(Wv, Wqkv + (size_t)2560 * 2048, 2048, 512); // rows 2560..3071
  wtrans<<<dim3(32, 32), 256, 0, stream>>>(Wo, Wot, 2048, 2048);
  // fused QKV projection + RoPE + repack (writes Qbf/Kbf/Vtb directly)
  gemm_qkv<<<768, 256, 0, stream>>>(xb, Wqkv, cosT, sinT, Qbf, Kbf, Vtb);
  attn_fwd<<<1024, 256, 0, stream>>>(Qbf, Kbf, Vtb, Att);
  gemm_bt<float><<<512, 256, 0, stream>>>(Att, Wot, out, 4096, 2048, 2048, 16);
}

// Round 13
// 189.867 us; speedup vs baseline: 1.0900x; 1.0900x over previous
//
#include <hip/hip_runtime.h>
#include <hip/hip_bf16.h>
#include <type_traits>

#define DEV __device__ __forceinline__

typedef __attribute__((ext_vector_type(4))) float f32x4;
typedef __attribute__((ext_vector_type(16))) float f32x16;
typedef __attribute__((ext_vector_type(8))) short short8;

static constexpr int Bc = 2, Sc = 2048, HQc = 32, HKVc = 8;

DEV unsigned short f2bf(float f) {
  union { float f; unsigned u; } v; v.f = f;
  unsigned r = v.u + 0x7fffu + ((v.u >> 16) & 1u);
  return (unsigned short)(r >> 16);
}
DEV float bf2f(unsigned short u) {
  union { unsigned u; float f; } v; v.u = ((unsigned)u) << 16;
  return v.f;
}

typedef const unsigned __attribute__((address_space(1)))* gp1;
typedef unsigned __attribute__((address_space(3)))* lp3;
DEV void gload16(const void* g, void* l) {
  __builtin_amdgcn_global_load_lds((gp1)g, (lp3)l, 16, 0, 0);
}

DEV unsigned cvt_pk_bf16(float lo, float hi) {
  unsigned r;
  asm("v_cvt_pk_bf16_f32 %0, %1, %2" : "=v"(r) : "v"(lo), "v"(hi));
  return r;
}
DEV void pl32swap(unsigned& a, unsigned& b) {
  asm("v_permlane32_swap_b32 %0, %1" : "+v"(a), "+v"(b));
}

// ---------------- prep: cast_x + 4x wtrans merged (flat grid, branch by bid) ----------------
// bid 0..8191        : cast x f32->bf16 (1024 f32/block)
// bid 8192..9215     : wtrans Wq  -> Wqkv rows 0..2047    (32x32)
// bid 9216..9471     : wtrans Wk  -> Wqkv rows 2048..2559 (8x32)
// bid 9472..9727     : wtrans Wv  -> Wqkv rows 2560..3071 (8x32)
// bid 9728..10751    : wtrans Wo  -> Wot                  (32x32)
__global__ __launch_bounds__(256) void prep(const float* __restrict__ x,
                                            const float* __restrict__ Wq,
                                            const float* __restrict__ Wk,
                                            const float* __restrict__ Wv,
                                            const float* __restrict__ Wo,
                                            unsigned short* __restrict__ xb,
                                            unsigned short* __restrict__ Wqkv,
                                            unsigned short* __restrict__ Wot) {
  __shared__ float t[64][65];
  const int bid = blockIdx.x;
  const int tid = threadIdx.x;
  if (bid < 8192) {
    const size_t i = (size_t)bid * 256 + tid;
    const float4 v = reinterpret_cast<const float4*>(x)[i];
    ushort4 o;
    o.x = f2bf(v.x); o.y = f2bf(v.y); o.z = f2bf(v.z); o.w = f2bf(v.w);
    reinterpret_cast<ushort4*>(xb)[i] = o;
    return;
  }
  const int tbl = bid - 8192;
  const float* in; unsigned short* out; int N, bx, by;
  if (tbl < 1024) { in = Wq; out = Wqkv; N = 2048; bx = tbl & 31; by = tbl >> 5; }
  else if (tbl < 1280) { const int t2 = tbl - 1024; in = Wk; out = Wqkv + (size_t)2048 * 2048; N = 512; bx = t2 & 7; by = t2 >> 3; }
  else if (tbl < 1536) { const int t2 = tbl - 1280; in = Wv; out = Wqkv + (size_t)2560 * 2048; N = 512; bx = t2 & 7; by = t2 >> 3; }
  else { const int t2 = tbl - 1536; in = Wo; out = Wot; N = 2048; bx = t2 & 31; by = t2 >> 5; }
  const int K = 2048;
  const int n0 = bx * 64, k0 = by * 64;
#pragma unroll
  for (int p = 0; p < 4; ++p) {
    const int kr = p * 16 + (tid >> 4);
    const int c = (tid & 15) * 4;
    const float4 v = *reinterpret_cast<const float4*>(&in[(size_t)(k0 + kr) * N + n0 + c]);
    t[c + 0][kr] = v.x; t[c + 1][kr] = v.y; t[c + 2][kr] = v.z; t[c + 3][kr] = v.w;
  }
  __syncthreads();
  const int n = tid >> 2, kc = (tid & 3) * 16;
  union { unsigned short u[16]; uint4 q[2]; } o;
#pragma unroll
  for (int e = 0; e < 16; ++e) o.u[e] = f2bf(t[n][kc + e]);
  uint4* dst = reinterpret_cast<uint4*>(&out[(size_t)(n0 + n) * K + k0 + kc]);
  dst[0] = o.q[0]; dst[1] = o.q[1];
}

// ---------------- GEMM: C(MxN) = A(MxK,bf16) * Bt(NxK,bf16)^T, m97 structure ----------------
// flat 1D grid with bijective XCD swizzle (m204)
template <typename CT>
__global__ __launch_bounds__(256) void gemm_bt(const unsigned short* __restrict__ A,
                                               const unsigned short* __restrict__ Bt,
                                               CT* __restrict__ C, int M, int N, int K,
                                               int gx) {
  const int nwg = gridDim.x;
  int bid = blockIdx.x;
  {
    const int qq = nwg >> 3, rr = nwg & 7;
    const int xcd = bid & 7, lid = bid >> 3;
    bid = (xcd < rr ? xcd * (qq + 1) : rr * (qq + 1) + (xcd - rr) * qq) + lid;
  }
  const int m0 = (bid / gx) * 128, n0 = (bid % gx) * 128;
  __shared__ __align__(16) unsigned short As[128 * 64];
  __shared__ __align__(16) unsigned short Bs[128 * 64];
  const int tid = threadIdx.x;
  const int w = tid >> 6, lane = tid & 63;
  const int g = lane >> 4, lm = lane & 15;
  const int wr = w >> 1, wc = w & 1;
  f32x4 acc[4][4] = {};
  const int nk = K >> 6;
  const char* Abase = (const char*)(A + (size_t)m0 * K);
  const char* Bbase = (const char*)(Bt + (size_t)n0 * K);
  const int off = w * 4096 + 16 * lane;
  for (int kt = 0; kt < nk; ++kt) {
    __syncthreads();
#pragma unroll
    for (int i = 0; i < 4; ++i) {
      const int o = off + i * 1024;
      const int row = o >> 7;
      const int kbs = (o & 127) ^ ((row & 7) << 4);
      const size_t gof = (size_t)row * (2 * K) + (size_t)kt * 128 + kbs;
      gload16(Abase + gof, (char*)As + (w * 4096 + i * 1024));
      gload16(Bbase + gof, (char*)Bs + (w * 4096 + i * 1024));
    }
    __syncthreads();
#pragma unroll
    for (int ks = 0; ks < 2; ++ks) {
      short8 af[4], bfr[4];
#pragma unroll
      for (int i = 0; i < 4; ++i) {
        const int ar = wr * 64 + i * 16 + lm;
        af[i] = *reinterpret_cast<const short8*>((const char*)As + ar * 128 + (((ks * 4 + g) ^ (ar & 7)) << 4));
        const int br = wc * 64 + i * 16 + lm;
        bfr[i] = *reinterpret_cast<const short8*>((const char*)Bs + br * 128 + (((ks * 4 + g) ^ (br & 7)) << 4));
      }
#pragma unroll
      for (int i = 0; i < 4; ++i)
#pragma unroll
        for (int j = 0; j < 4; ++j)
          acc[i][j] = __builtin_amdgcn_mfma_f32_16x16x32_bf16(af[i], bfr[j], acc[i][j], 0, 0, 0);
    }
  }
#pragma unroll
  for (int i = 0; i < 4; ++i)
#pragma unroll
    for (int j = 0; j < 4; ++j)
#pragma unroll
      for (int r = 0; r < 4; ++r) {
        const size_t idx = (size_t)(m0 + wr * 64 + i * 16 + g * 4 + r) * N + (n0 + wc * 64 + j * 16 + lm);
        if constexpr (std::is_same<CT, float>::value) C[idx] = acc[i][j][r];
        else C[idx] = (CT)f2bf(acc[i][j][r]);
      }
}

// ---------------- post: ropeQ + ropeK + repack_v merged (flat grid) ----------------
// bid 0..16383   : rope Q (NH=32, colOff 0, qs=0.125*log2e)
// bid 16384..20479: rope K (NH=8, colOff 2048, qs=1)
// bid 20480..20991: repack V (cols 2560+, transpose)
DEV void rope_body(const unsigned short* __restrict__ Xp, const float* __restrict__ cosT,
                   const float* __restrict__ sinT, unsigned short* __restrict__ Xb,
                   int NH, int colOff, float qs, int bid, int tid) {
  const size_t i = (size_t)bid * 256 + tid;
  const int d = (int)(i & 31);
  const size_t t = i >> 5;
  const int h = (int)(t % NH);
  const size_t row = t / NH;          // b*S + s
  const int s = (int)(row & (Sc - 1));
  const size_t b = row >> 11;
  const size_t ib = row * 3072 + colOff + (size_t)h * 64 + d;
  const float q1 = bf2f(Xp[ib]);
  const float q2 = bf2f(Xp[ib + 32]);
  const float c = cosT[s * 64 + d], sn = sinT[s * 64 + d];
  const size_t ob = ((b * NH + h) * (size_t)Sc + s) * 64 + d;
  Xb[ob] = f2bf((q1 * c - q2 * sn) * qs);
  Xb[ob + 32] = f2bf((q2 * c + q1 * sn) * qs);
}

__global__ __launch_bounds__(256) void post(const unsigned short* __restrict__ QKVp,
                                            const float* __restrict__ cosT,
                                            const float* __restrict__ sinT,
                                            unsigned short* __restrict__ Qbf,
                                            unsigned short* __restrict__ Kbf,
                                            unsigned short* __restrict__ Vtb) {
  __shared__ int t[64][65];
  const int bid = blockIdx.x;
  const int tid = threadIdx.x;
  if (bid < 16384) {
    rope_body(QKVp, cosT, sinT, Qbf, HQc, 0, 0.125f * 1.44269504089f, bid, tid);
    return;
  }
  if (bid < 20480) {
    rope_body(QKVp, cosT, sinT, Kbf, HKVc, 2048, 1.0f, bid - 16384, tid);
    return;
  }
  const int tv = bid - 20480;          // 0..511
  const int bh = tv >> 5;
  const int s0 = (tv & 31) * 64;
  const int b = bh >> 3, hk = bh & 7;
#pragma unroll
  for (int p = 0; p < 2; ++p) {
    const int sr = p * 32 + (tid >> 3);
    const int c = (tid & 7) * 8;
    short8 v = *reinterpret_cast<const short8*>(&QKVp[(size_t)(b * Sc + s0 + sr) * 3072 + 2560 + hk * 64 + c]);
#pragma unroll
    for (int e = 0; e < 8; ++e) t[c + e][sr] = (unsigned short)v[e];
  }
  __syncthreads();
  const int d = tid >> 2, scol = (tid & 3) * 16;
  union { unsigned short u[16]; uint4 q[2]; } o;
#pragma unroll
  for (int e = 0; e < 16; ++e) o.u[e] = (unsigned short)t[d][scol + e];
  uint4* dst = reinterpret_cast<uint4*>(&Vtb[((size_t)bh * 64 + d) * Sc + s0 + scol]);
  dst[0] = o.q[0]; dst[1] = o.q[1];
}

// ---------------- causal GQA flash attention, 64-row q-tile + ones-MFMA l + setprio ----------------
// 256 thr = 2 heads x 2 halves, grid 1024 = 4 blocks/CU, balanced long-first decode,
// row-sum on matrix pipe (r9 structure, 202us known-good)
__global__ __launch_bounds__(256, 4) void attn_fwd(const unsigned short* __restrict__ Qb,
                                                   const unsigned short* __restrict__ Kb,
                                                   const unsigned short* __restrict__ Vt,
                                                   unsigned short* __restrict__ Ob) {
  __shared__ __align__(16) char sm[32768];
  const int tid = threadIdx.x;
  const int w = tid >> 6, lane = tid & 63;
  const int lane31 = lane & 31, hi = lane >> 5;
  const int hi16 = hi * 16;
  const int hl = w >> 1, wh = w & 1;
  const int bid = blockIdx.x;
  const int hk = bid & 7;
  const int sub = (bid >> 3) & 3;
  const int tq = (bid >> 5) & 7;
  const int quarter = bid >> 8;
  int qt;
  if (quarter == 0) qt = 31 - tq;
  else if (quarter == 1) qt = 16 + tq;
  else if (quarter == 2) qt = 15 - tq;
  else qt = tq;
  const int b = sub >> 1, hp = sub & 1;
  const int h = hk * 4 + hp * 2 + hl;
  const int q0 = qt * 64;
  const char* Kbase = (const char*)(Kb + (size_t)(b * HKVc + hk) * Sc * 64);
  const char* Vbase = (const char*)(Vt + (size_t)(b * HKVc + hk) * 64 * Sc);
  const unsigned short* Qp = Qb + (((size_t)(b * HQc + h) * Sc) + q0 + wh * 32 + lane31) * 64;
  short8 qf[4];
#pragma unroll
  for (int c = 0; c < 4; ++c)
    qf[c] = *reinterpret_cast<const short8*>(Qp + c * 16 + hi * 8);

  f32x16 acc[2] = {};
  f32x16 accl = {};
  const int qlocal = wh * 32 + lane31 - 4 * hi;
  union { unsigned u[4]; short8 s; } onesu;
  onesu.u[0] = onesu.u[1] = onesu.u[2] = onesu.u[3] = 0x3f803f80u;
  const short8 ones8 = onesu.s;

  const int so0 = tid * 16;
  auto stage = [&](int kt, int buf) {
    char* Kd = sm + buf * 16384;
    char* Vd = sm + buf * 16384 + 8192;
#pragma unroll
    for (int q = 0; q < 2; ++q) {
      const int o = q * 4096 + so0;
      const int srow = o >> 7;
      const int kbs = (o & 127) ^ ((srow & 7) << 4);
      const int ld = q * 4096 + w * 1024;
      gload16(Kbase + (size_t)(kt * 64 + srow) * 128 + kbs, Kd + ld);
      gload16(Vbase + (size_t)srow * (Sc * 2) + (size_t)kt * 128 + kbs, Vd + ld);
    }
  };

  stage(0, 0);
  __syncthreads();
  for (int kt = 0; kt <= qt; ++kt) {
    const int cur = kt & 1;
    if (kt < qt) stage(kt + 1, cur ^ 1);
    const char* Kbuf = sm + cur * 16384;
    const char* Vbuf = sm + cur * 16384 + 8192;
    const bool dg = (kt == qt);
    const bool do_hi = !dg || (wh == 1);
    short8 pf[4];
    {
      f32x16 st = {};
      __builtin_amdgcn_s_setprio(1);
#pragma unroll
      for (int c = 0; c < 4; ++c) {
        const int row = lane31;
        const short8 kf = *reinterpret_cast<const short8*>(Kbuf + row * 128 + ((c * 32 + hi16) ^ ((row & 7) << 4)));
        st = __builtin_amdgcn_mfma_f32_32x32x16_bf16(kf, qf[c], st, 0, 0, 0);
      }
      __builtin_amdgcn_s_setprio(0);
      if (dg && wh == 0) {
#pragma unroll
        for (int r = 0; r < 16; ++r) {
          const int kl = (r & 3) + 8 * (r >> 2);
          st[r] = exp2f(kl > qlocal ? -1e30f : st[r]);
        }
      } else {
#pragma unroll
        for (int r = 0; r < 16; ++r) st[r] = exp2f(st[r]);
      }
      union { unsigned u[4]; short8 s; } x, y;
      unsigned a0 = cvt_pk_bf16(st[0], st[1]), b0 = cvt_pk_bf16(st[4], st[5]);
      pl32swap(a0, b0);
      unsigned a1 = cvt_pk_bf16(st[2], st[3]), b1 = cvt_pk_bf16(st[6], st[7]);
      pl32swap(a1, b1);
      x.u[0] = a0; x.u[1] = a1; x.u[2] = b0; x.u[3] = b1; pf[0] = x.s;
      unsigned a2 = cvt_pk_bf16(st[8], st[9]), b2 = cvt_pk_bf16(st[12], st[13]);
      pl32swap(a2, b2);
      unsigned a3 = cvt_pk_bf16(st[10], st[11]), b3 = cvt_pk_bf16(st[14], st[15]);
      pl32swap(a3, b3);
      y.u[0] = a2; y.u[1] = a3; y.u[2] = b2; y.u[3] = b3; pf[1] = y.s;
    }
    if (do_hi) {
      f32x16 st = {};
      __builtin_amdgcn_s_setprio(1);
#pragma unroll
      for (int c = 0; c < 4; ++c) {
        const int row = 32 + lane31;
        const short8 kf = *reinterpret_cast<const short8*>(Kbuf + row * 128 + ((c * 32 + hi16) ^ ((row & 7) << 4)));
        st = __builtin_amdgcn_mfma_f32_32x32x16_bf16(kf, qf[c], st, 0, 0, 0);
      }
      __builtin_amdgcn_s_setprio(0);
      if (dg) {
        const int rhs = qlocal - 32;
#pragma unroll
        for (int r = 0; r < 16; ++r) {
          const int kl = (r & 3) + 8 * (r >> 2);
          st[r] = exp2f(kl > rhs ? -1e30f : st[r]);
        }
      } else {
#pragma unroll
        for (int r = 0; r < 16; ++r) st[r] = exp2f(st[r]);
      }
      union { unsigned u[4]; short8 s; } x, y;
      unsigned a0 = cvt_pk_bf16(st[0], st[1]), b0 = cvt_pk_bf16(st[4], st[5]);
      pl32swap(a0, b0);
      unsigned a1 = cvt_pk_bf16(st[2], st[3]), b1 = cvt_pk_bf16(st[6], st[7]);
      pl32swap(a1, b1);
      x.u[0] = a0; x.u[1] = a1; x.u[2] = b0; x.u[3] = b1; pf[2] = x.s;
      unsigned a2 = cvt_pk_bf16(st[8], st[9]), b2 = cvt_pk_bf16(st[12], st[13]);
      pl32swap(a2, b2);
      unsigned a3 = cvt_pk_bf16(st[10], st[11]), b3 = cvt_pk_bf16(st[14], st[15]);
      pl32swap(a3, b3);
      y.u[0] = a2; y.u[1] = a3; y.u[2] = b2; y.u[3] = b3; pf[3] = y.s;
    }
    __builtin_amdgcn_s_setprio(1);
#pragma unroll
    for (int dt = 0; dt < 2; ++dt) {
      const int row = dt * 32 + lane31;
      const int rx = (row & 7) << 4;
#pragma unroll
      for (int c = 0; c < 2; ++c) {
        const short8 vf = *reinterpret_cast<const short8*>(Vbuf + row * 128 + ((c * 32 + hi16) ^ rx));
        acc[dt] = __builtin_amdgcn_mfma_f32_32x32x16_bf16(pf[c], vf, acc[dt], 0, 0, 0);
      }
      if (do_hi) {
#pragma unroll
        for (int c = 2; c < 4; ++c) {
          const short8 vf = *reinterpret_cast<const short8*>(Vbuf + row * 128 + ((c * 32 + hi16) ^ rx));
          acc[dt] = __builtin_amdgcn_mfma_f32_32x32x16_bf16(pf[c], vf, acc[dt], 0, 0, 0);
        }
      }
    }
    accl = __builtin_amdgcn_mfma_f32_32x32x16_bf16(pf[0], ones8, accl, 0, 0, 0);
    accl = __builtin_amdgcn_mfma_f32_32x32x16_bf16(pf[1], ones8, accl, 0, 0, 0);
    if (do_hi) {
      accl = __builtin_amdgcn_mfma_f32_32x32x16_bf16(pf[2], ones8, accl, 0, 0, 0);
      accl = __builtin_amdgcn_mfma_f32_32x32x16_bf16(pf[3], ones8, accl, 0, 0, 0);
    }
    __builtin_amdgcn_s_setprio(0);
    __syncthreads();
  }
  unsigned short* Os = (unsigned short*)sm;
#pragma unroll
  for (int r = 0; r < 16; ++r) {
    const int cr = (r & 3) + 8 * (r >> 2) + 4 * hi;
    const float inv = 1.f / accl[r];
    const int row = wh * 32 + cr;
#pragma unroll
    for (int dt = 0; dt < 2; ++dt)
      Os[row * 128 + hl * 64 + dt * 32 + lane31] = f2bf(acc[dt][r] * inv);
  }
  __syncthreads();
  unsigned short* Op = Ob + (size_t)(b * Sc + q0) * (HQc * 64) + (hk * 4 + hp * 2) * 64;
#pragma unroll
  for (int i = 0; i < 4; ++i) {
    const int cid = i * 256 + tid;
    const int row = cid >> 4;
    const int cb = (cid & 15) * 16;
    const uint4 v = *reinterpret_cast<const uint4*>(sm + row * 256 + cb);
    *reinterpret_cast<uint4*>((char*)(Op + (size_t)row * (HQc * 64)) + cb) = v;
  }
}

extern "C" void kernel_launch(void* const* d_in, const int* in_sizes, int n_in,
                              void* d_out, int out_size, void* d_ws, size_t ws_size,
                              hipStream_t stream) {
  (void)in_sizes; (void)n_in; (void)out_size; (void)ws_size;
  const float* x    = (const float*)d_in[0];
  const float* cosT = (const float*)d_in[1];
  const float* sinT = (const float*)d_in[2];
  // d_in[3] = mask: deterministic causal, not read
  const float* Wq = (const float*)d_in[4];
  const float* Wk = (const float*)d_in[5];
  const float* Wv = (const float*)d_in[6];
  const float* Wo = (const float*)d_in[7];
  float* out = (float*)d_out;
  char* ws = (char*)d_ws;
  const size_t MB = (size_t)1 << 20;
  // Workspace (60MB):
  unsigned short* xb   = (unsigned short*)(ws + 0 * MB);   // 16MB (x bf16; reused as Att)
  unsigned short* Wqkv = (unsigned short*)(ws + 16 * MB);  // 12MB packed [3072][2048] bf16
  unsigned short* Wot  = (unsigned short*)(ws + 28 * MB);  // 8MB
  unsigned short* Qbf  = (unsigned short*)(ws + 36 * MB);  // 16MB ([B][HQ][S][64])
  unsigned short* Kbf  = (unsigned short*)(ws + 52 * MB);  // 4MB
  unsigned short* Vtb  = (unsigned short*)(ws + 56 * MB);  // 4MB  -> 60MB total
  unsigned short* Att  = (unsigned short*)(ws + 0 * MB);   // reuse xb (dead after QKV GEMM)
  // Packed QKV GEMM output in d_out (24MB of 32MB; dead before final GEMM):
  unsigned short* QKVp = (unsigned short*)d_out;           // [4096][3072] bf16

  prep<<<10752, 256, 0, stream>>>(x, Wq, Wk, Wv, Wo, xb, Wqkv, Wot);
  gemm_bt<unsigned short><<<768, 256, 0, stream>>>(xb, Wqkv, QKVp, 4096, 3072, 2048, 24);
  post<<<20992, 256, 0, stream>>>(QKVp, cosT, sinT, Qbf, Kbf, Vtb);
  attn_fwd<<<1024, 256, 0, stream>>>(Qbf, Kbf, Vtb, Att);
  gemm_bt<float><<<512, 256, 0, stream>>>(Att, Wot, out, 4096, 2048, 2048, 16);
}